// Round 1
// 296.030 us; speedup vs baseline: 1.3037x; 1.3037x over previous
//
#include <hip/hip_runtime.h>
#include <hip/hip_bf16.h>

#define N_B 1024
#define N_ITEMS 100000
#define N_CLUSTERS 10
#define N_D 64
#define MAXT 6272            // padded tile capacity; NT <= 6260 always
#define GYB 98               // k3 j-block dim (was 49)
#define RUN 16               // tiles per wave: 98*4*16 = 6272 exactly
#define K1B 392              // k1 blocks: 392*4 waves*64 rows = 100352

typedef __attribute__((ext_vector_type(8))) short short8;
typedef __attribute__((ext_vector_type(4))) float f32x4;
typedef __attribute__((ext_vector_type(4))) unsigned u32x4;

#if defined(__has_builtin)
#if __has_builtin(__builtin_amdgcn_exp2f)
#define EXP2F(x) __builtin_amdgcn_exp2f(x)
#endif
#endif
#ifndef EXP2F
#define EXP2F(x) exp2f(x)
#endif

// bf16 RNE split helpers (bit-level; sign-safe)
__device__ __forceinline__ unsigned short bf16_rne(float x) {
  unsigned u = __float_as_uint(x);
  u += 0x7FFFu + ((u >> 16) & 1u);
  return (unsigned short)(u >> 16);
}
__device__ __forceinline__ float bf16_f(unsigned short b) {
  return __uint_as_float(((unsigned)b) << 16);
}

// pack low/high 16-bit halves of 8 dwords into a short8 via v_perm_b32
__device__ __forceinline__ short8 pack_even(u32x4 a, u32x4 b) {
  union { unsigned u[4]; short8 s; } r;
  r.u[0] = __builtin_amdgcn_perm(a[1], a[0], 0x05040100u);
  r.u[1] = __builtin_amdgcn_perm(a[3], a[2], 0x05040100u);
  r.u[2] = __builtin_amdgcn_perm(b[1], b[0], 0x05040100u);
  r.u[3] = __builtin_amdgcn_perm(b[3], b[2], 0x05040100u);
  return r.s;
}
__device__ __forceinline__ short8 pack_odd(u32x4 a, u32x4 b) {
  union { unsigned u[4]; short8 s; } r;
  r.u[0] = __builtin_amdgcn_perm(a[1], a[0], 0x07060302u);
  r.u[1] = __builtin_amdgcn_perm(a[3], a[2], 0x07060302u);
  r.u[2] = __builtin_amdgcn_perm(b[1], b[0], 0x07060302u);
  r.u[3] = __builtin_amdgcn_perm(b[3], b[2], 0x07060302u);
  return r.s;
}

// ---------------------------------------------------------------------------
// Kernel 1: per-block partial S1/counts (unchanged from R10).
// ---------------------------------------------------------------------------
__global__ __launch_bounds__(256) void k1_segsum(
    const int* __restrict__ cl, const float* __restrict__ W1,
    float* __restrict__ S1p, float* __restrict__ cntp) {
  __shared__ float s1[4][N_CLUSTERS][N_D];
  __shared__ float scnt[4][N_CLUSTERS];
  int t = threadIdx.x;
  int wave = t >> 6, lane = t & 63;

  float a[N_CLUSTERS], cn[N_CLUSTERS];
#pragma unroll
  for (int k = 0; k < N_CLUSTERS; ++k) { a[k] = 0.f; cn[k] = 0.f; }

  int gw = blockIdx.x * 4 + wave;              // 0..1567
  int r0 = gw * 64;
#pragma unroll 1
  for (int b = 0; b < 8; ++b) {
    int i0 = r0 + b * 8;
    float w[8];
    int c[8];
    if (i0 + 8 <= N_ITEMS) {
#pragma unroll
      for (int j = 0; j < 8; ++j) {
        c[j] = cl[i0 + j];                     // wave-uniform -> s_load
        w[j] = W1[(size_t)(i0 + j) * N_D + lane];
      }
    } else {
#pragma unroll
      for (int j = 0; j < 8; ++j) {
        int i = i0 + j;
        bool ok = i < N_ITEMS;
        c[j] = ok ? cl[i] : -1;
        w[j] = ok ? W1[(size_t)i * N_D + lane] : 0.f;
      }
    }
#pragma unroll
    for (int j = 0; j < 8; ++j)
#pragma unroll
      for (int k = 0; k < N_CLUSTERS; ++k) {
        bool m = (c[j] == k);
        a[k] += m ? w[j] : 0.f;
        cn[k] += m ? 1.f : 0.f;
      }
  }
#pragma unroll
  for (int k = 0; k < N_CLUSTERS; ++k) s1[wave][k][lane] = a[k];
  if (lane == 0) {
#pragma unroll
    for (int k = 0; k < N_CLUSTERS; ++k) scnt[wave][k] = cn[k];
  }
  __syncthreads();
  const float* fs1 = (const float*)s1;
  for (int i = t; i < N_CLUSTERS * N_D; i += 256) {
    S1p[blockIdx.x * 640 + i] =
        fs1[i] + fs1[640 + i] + fs1[1280 + i] + fs1[1920 + i];
  }
  if (t < N_CLUSTERS) {
    cntp[blockIdx.x * N_CLUSTERS + t] =
        scnt[0][t] + scnt[1][t] + scnt[2][t] + scnt[3][t];
  }
}

// ---------------------------------------------------------------------------
// Kernel 1r: single block. Reduce partials; segment bases; tile tables;
// zero cursors; fill inv[] pad slots (in-segment AND trailing slots — k3 now
// dereferences inv for pad tiles, so the whole [end, MAXT*16) tail must be 0).
// ---------------------------------------------------------------------------
__global__ __launch_bounds__(256) void k1r(
    const float* __restrict__ S1p, const float* __restrict__ cntp,
    float* __restrict__ S1g, float* __restrict__ cntF, int* __restrict__ meta,
    int* __restrict__ tileclu, int* __restrict__ nvalid,
    int* __restrict__ inv, int* __restrict__ cursor) {
  __shared__ int baseS[11];
  __shared__ int cntI[N_CLUSTERS];
  int t = threadIdx.x;
  if (t < 16) cursor[t] = 0;
  for (int i = t; i < 640; i += 256) {
    float s = 0.f;
    for (int b = 0; b < K1B; ++b) s += S1p[b * 640 + i];
    S1g[i] = s;
  }
  if (t < N_CLUSTERS) {
    float s = 0.f;
    for (int b = 0; b < K1B; ++b) s += cntp[b * N_CLUSTERS + t];
    cntF[t] = s;
    cntI[t] = (int)(s + 0.5f);
  }
  __syncthreads();
  if (t == 0) {
    int acc = 0;
    for (int c = 0; c < N_CLUSTERS; ++c) {
      baseS[c] = acc;
      acc += ((cntI[c] + 15) >> 4) << 4;       // 16-align each segment
    }
    baseS[10] = acc;
    for (int c = 0; c < 11; ++c) meta[c] = baseS[c];
    meta[11] = acc >> 4;                       // NT
  }
  __syncthreads();
  int NT = baseS[10] >> 4;
  for (int jt = t; jt < MAXT; jt += 256) {
    int c = 0, nv = 0;
    if (jt < NT) {
      int p0 = jt * 16;
      for (int k = 0; k < N_CLUSTERS; ++k)
        if (p0 >= baseS[k] && p0 < baseS[k + 1]) c = k;
      nv = min(16, cntI[c] - (p0 - baseS[c]));
      if (nv < 0) nv = 0;
    }
    tileclu[jt] = c;
    nvalid[jt] = nv;
  }
  int end = baseS[10];
  for (int p = t; p < end; p += 256) {         // fill in-segment pad slots
    int c = 0;
    for (int k = 0; k < N_CLUSTERS; ++k)
      if (p >= baseS[k] && p < baseS[k + 1]) c = k;
    if (p - baseS[c] >= cntI[c]) inv[p] = 0;
  }
  for (int p = end + t; p < MAXT * 16; p += 256) inv[p] = 0;  // trailing pads
}

// ---------------------------------------------------------------------------
// Kernel 1c: inverse perm (pos -> item), block-aggregated ranking.
// Also zeroes the atomic bucket array (overlays dead S1p; k1r already ran).
// ---------------------------------------------------------------------------
__global__ __launch_bounds__(256) void k1c(
    const int* __restrict__ cl, const int* __restrict__ meta,
    int* __restrict__ cursor, int* __restrict__ inv,
    float* __restrict__ bucket) {
  __shared__ int wn[4][N_CLUSTERS];
  __shared__ int bb[N_CLUSTERS];
  int i = blockIdx.x * 256 + threadIdx.x;
  if (i < N_B * N_CLUSTERS) bucket[i] = 0.f;   // zero 10240 floats
  int wave = threadIdx.x >> 6, lane = threadIdx.x & 63;
  int c = (i < N_ITEMS) ? cl[i] : -1;
  unsigned long long m[N_CLUSTERS];
#pragma unroll
  for (int k = 0; k < N_CLUSTERS; ++k) {
    m[k] = __ballot(c == k);
    if (lane == 0) wn[wave][k] = __popcll(m[k]);
  }
  __syncthreads();
  if (threadIdx.x < N_CLUSTERS) {
    int tot = wn[0][threadIdx.x] + wn[1][threadIdx.x] + wn[2][threadIdx.x] +
              wn[3][threadIdx.x];
    bb[threadIdx.x] = tot ? atomicAdd(&cursor[threadIdx.x], tot) : 0;
  }
  __syncthreads();
  if (c >= 0) {
    int rank = 0;
#pragma unroll
    for (int k = 0; k < N_CLUSTERS; ++k)
      if (c == k) rank = __popcll(m[k] & ((1ull << lane) - 1ull));
    int wsum = 0;
    for (int w2 = 0; w2 < wave; ++w2) wsum += wn[w2][c];
    inv[meta[c] + bb[c] + wsum + rank] = i;
  }
}

// ---------------------------------------------------------------------------
// Kernel W2P: transpose + bf16 hi/lo split of W2 (64 x 100000 fp32 ->
// item-major 100000 x 64 packed hi|lo<<16 dwords). Replaces k0_pack's
// ~410MB scattered-line gather with 51MB of clean streaming traffic; k3
// gathers B-fragments directly from W2P as dwordx4.
// ---------------------------------------------------------------------------
__global__ __launch_bounds__(256) void w2p_k(const float* __restrict__ W2,
                                             unsigned* __restrict__ W2P) {
  __shared__ unsigned tile[64][65];            // +1 pad: conflict-free
  int t = threadIdx.x;
  int c0 = blockIdx.x * 64;
  int cl_ = t & 63;
  int r0 = t >> 6;
  bool okr = (c0 + cl_) < N_ITEMS;
#pragma unroll
  for (int rr = 0; rr < 16; ++rr) {
    int r = rr * 4 + r0;
    float x = okr ? W2[(size_t)r * N_ITEMS + c0 + cl_] : 0.f;
    unsigned short hi = bf16_rne(x);
    unsigned short lo = bf16_rne(x - bf16_f(hi));
    tile[cl_][r] = (unsigned)hi | ((unsigned)lo << 16);
  }
  __syncthreads();
  int rw = t & 63;
  int cw = t >> 6;
#pragma unroll
  for (int cb = 0; cb < 16; ++cb) {
    int c = c0 + cb * 4 + cw;
    if (c < N_ITEMS) W2P[(size_t)c * N_D + rw] = tile[cb * 4 + cw][rw];
  }
}

// ---------------------------------------------------------------------------
// Kernel 3 (hot, restructured):
//  - builds its own A-fragments in-block from inp @ S1g (kills k2_h/k2b and
//    the hfrag global round-trip); log2(e) folded in -> exp2 in the loop
//  - gathers B directly from W2P as 4x dwordx4 (kills k0_pack and pk)
//  - register-accumulates exp results across tiles; the 16-lane shfl
//    reduction runs only on cluster-change/run-end (~1.1x per 16-tile run
//    instead of per tile) -> removes the per-tile LDS-pipe serial chains
//  - atomicAdd flush into one global bucket (no bkt LDS, no partials, no
//    per-block zero/reduce); LDS 26.6KB -> 20.5KB
//  - RUN 32->16, GYB 49->98: 1568 blocks, ~4 resident blocks/CU
//  - XCD swizzle keeps the 16 x-blocks sharing a y's W2P slice on one XCD
// ---------------------------------------------------------------------------
__global__ __launch_bounds__(256, 4) void k3_mfma(
    const unsigned* __restrict__ W2P, const float* __restrict__ inp,
    const float* __restrict__ S1g, const int* __restrict__ inv,
    const int* __restrict__ tileclu, const int* __restrict__ nvalid,
    float* __restrict__ bucket) {
  __shared__ short8 afl[16][64];               // 16 KB A-fragments
  __shared__ int linv[4][256];                 // 4 KB per-wave col staging
  int t = threadIdx.x;
  int wave = t >> 6, lane = t & 63;
  int l15 = lane & 15, quad = lane >> 4;

  // bijective XCD swizzle: 1568 blocks = 8 XCDs x 196
  int lid = blockIdx.y * 16 + blockIdx.x;
  int nid = (lid & 7) * (GYB * 16 / 8) + (lid >> 3);
  int bx = nid & 15, by = nid >> 4;

  int jt0 = (by * 4 + wave) * RUN;             // jt0+RUN <= 6272 always

  {  // stage this run's inv slice (per-wave)
    const int* ip = inv + jt0 * 16;
#pragma unroll
    for (int q = 0; q < 4; ++q) linv[wave][q * 64 + lane] = ip[q * 64 + lane];
  }

  // build A fragments: h = inp @ S1g, * log2(e), bf16 hi/lo split
#pragma unroll
  for (int rep = 0; rep < 2; ++rep) {
    int id = rep * 256 + t;                    // 512 fragment slots
    int fl = id & 63;
    int ks = (id >> 6) & 1;
    int rtl = (id >> 7) & 3;
    int row = bx * 64 + rtl * 16 + (id & 15);
    int d0 = ks * 32 + ((id >> 4) & 3) * 8;
    float hv[8];
#pragma unroll
    for (int j = 0; j < 8; ++j) hv[j] = 0.f;
#pragma unroll
    for (int c = 0; c < N_CLUSTERS; ++c) {
      float ic = inp[row * N_CLUSTERS + c];
      const float* sp = S1g + c * N_D + d0;
#pragma unroll
      for (int j = 0; j < 8; ++j) hv[j] += ic * sp[j];
    }
    short8 hi8, lo8;
#pragma unroll
    for (int j = 0; j < 8; ++j) {
      float x = hv[j] * 1.44269504088896340736f;
      unsigned short us = bf16_rne(x);
      hi8[j] = (short)us;
      lo8[j] = (short)bf16_rne(x - bf16_f(us));
    }
    afl[(rtl * 2 + ks) * 2 + 0][fl] = hi8;
    afl[(rtl * 2 + ks) * 2 + 1][fl] = lo8;
  }
  __syncthreads();

  f32x4 acc[4];
#pragma unroll
  for (int rt = 0; rt < 4; ++rt) acc[rt] = (f32x4){0.f, 0.f, 0.f, 0.f};

  u32x4 va, vb, vc, vd;
  int cc, nv;
  {
    int col = linv[wave][l15];
    const unsigned* bp = W2P + (size_t)col * N_D + quad * 8;
    va = *(const u32x4*)(bp);
    vb = *(const u32x4*)(bp + 4);
    vc = *(const u32x4*)(bp + 32);
    vd = *(const u32x4*)(bp + 36);
    cc = tileclu[jt0];
    nv = nvalid[jt0];
  }

  for (int it = 0; it < RUN; ++it) {
    short8 bh0, bl0, bh1, bl1;
    bool act = (nv > 0);                       // wave-uniform
    if (act) {                                 // unpack frees v for prefetch
      bh0 = pack_even(va, vb);
      bl0 = pack_odd(va, vb);
      bh1 = pack_even(vc, vd);
      bl1 = pack_odd(vc, vd);
    }
    int ccn = cc, nvn = 0;
    if (it + 1 < RUN) {                        // prefetch next tile into v
      int col = linv[wave][(it + 1) * 16 + l15];
      const unsigned* bp = W2P + (size_t)col * N_D + quad * 8;
      va = *(const u32x4*)(bp);
      vb = *(const u32x4*)(bp + 4);
      vc = *(const u32x4*)(bp + 32);
      vd = *(const u32x4*)(bp + 36);
      ccn = tileclu[jt0 + it + 1];
      nvn = nvalid[jt0 + it + 1];
    }
    if (act) {
#pragma unroll
      for (int rt = 0; rt < 4; ++rt) {
        short8 a00 = afl[rt * 4 + 0][lane];
        short8 a01 = afl[rt * 4 + 1][lane];
        short8 a10 = afl[rt * 4 + 2][lane];
        short8 a11 = afl[rt * 4 + 3][lane];
        f32x4 c = {0.f, 0.f, 0.f, 0.f};
        c = __builtin_amdgcn_mfma_f32_16x16x32_bf16(a00, bh0, c, 0, 0, 0);
        c = __builtin_amdgcn_mfma_f32_16x16x32_bf16(a00, bl0, c, 0, 0, 0);
        c = __builtin_amdgcn_mfma_f32_16x16x32_bf16(a01, bh0, c, 0, 0, 0);
        c = __builtin_amdgcn_mfma_f32_16x16x32_bf16(a10, bh1, c, 0, 0, 0);
        c = __builtin_amdgcn_mfma_f32_16x16x32_bf16(a10, bl1, c, 0, 0, 0);
        c = __builtin_amdgcn_mfma_f32_16x16x32_bf16(a11, bh1, c, 0, 0, 0);
        // C/D: col=lane&15 (item), row=quad*4+reg  [m89-verified]
        if (nv == 16) {
          acc[rt][0] += EXP2F(c[0]);
          acc[rt][1] += EXP2F(c[1]);
          acc[rt][2] += EXP2F(c[2]);
          acc[rt][3] += EXP2F(c[3]);
        } else {
          acc[rt][0] += (l15 < nv) ? EXP2F(c[0]) : 0.f;
          acc[rt][1] += (l15 < nv) ? EXP2F(c[1]) : 0.f;
          acc[rt][2] += (l15 < nv) ? EXP2F(c[2]) : 0.f;
          acc[rt][3] += (l15 < nv) ? EXP2F(c[3]) : 0.f;
        }
      }
    }
    if (it == RUN - 1 || ccn != cc) {          // flush (wave-uniform, rare)
#pragma unroll
      for (int rt = 0; rt < 4; ++rt) {
        float e0 = acc[rt][0], e1 = acc[rt][1];
        float e2 = acc[rt][2], e3 = acc[rt][3];
#pragma unroll
        for (int m = 1; m < 16; m <<= 1) {
          e0 += __shfl_xor(e0, m, 64);
          e1 += __shfl_xor(e1, m, 64);
          e2 += __shfl_xor(e2, m, 64);
          e3 += __shfl_xor(e3, m, 64);
        }
        if (l15 == 0) {
          int r = bx * 64 + rt * 16 + quad * 4;
          atomicAdd(&bucket[(r + 0) * N_CLUSTERS + cc], e0);
          atomicAdd(&bucket[(r + 1) * N_CLUSTERS + cc], e1);
          atomicAdd(&bucket[(r + 2) * N_CLUSTERS + cc], e2);
          atomicAdd(&bucket[(r + 3) * N_CLUSTERS + cc], e3);
        }
        acc[rt] = (f32x4){0.f, 0.f, 0.f, 0.f};
      }
    }
    cc = ccn;
    nv = nvn;
  }
}

// ---------------------------------------------------------------------------
// Kernel 4: normalize (softmax denom = per-row sum over clusters), /counts.
// ---------------------------------------------------------------------------
__global__ __launch_bounds__(320) void k4_fin(
    const float* __restrict__ bucket, const float* __restrict__ cntF,
    float* __restrict__ out) {
  __shared__ float bl[32][N_CLUSTERS];
  int t = threadIdx.x;                         // 0..319
  int r = t / N_CLUSTERS, c = t % N_CLUSTERS;
  int row = blockIdx.x * 32 + r;
  float s = bucket[row * N_CLUSTERS + c];
  bl[r][c] = s;
  __syncthreads();
  float tot = 0.f;
#pragma unroll
  for (int k = 0; k < N_CLUSTERS; ++k) tot += bl[r][k];
  out[row * N_CLUSTERS + c] = s / (tot * fmaxf(cntF[c], 1.f));
}

// ---------------------------------------------------------------------------
// Workspace layout (4-byte units), total 27.6 MB (was 28.7):
//   [0,640) S1g | [640,656) cntF | [656,672) meta | [672,688) cursor
//   [1024,7296) tileclu | [7296,13568) nvalid | [16384,116736) inv
//   [247808,6647808) W2P (item-major packed bf16 hi|lo dwords)
//   scratch (dead after k1r): [6647808,6898688) S1p | [6898688,6902608) cntp
//   bucket OVERLAYS S1p head: [6647808,6658048) — zeroed in k1c (after k1r),
//   atomically accumulated in k3, read in k4; stream-ordered.
// No memset needed: cursor + inv pads zeroed by k1r, bucket by k1c.
// ---------------------------------------------------------------------------
extern "C" void kernel_launch(void* const* d_in, const int* in_sizes, int n_in,
                              void* d_out, int out_size, void* d_ws, size_t ws_size,
                              hipStream_t stream) {
  const float* input = (const float*)d_in[0];   // (1024, 10) f32
  const int* cl      = (const int*)d_in[1];     // (100000,) i32
  const float* W1    = (const float*)d_in[2];   // (100000, 64) f32
  const float* W2    = (const float*)d_in[3];   // (64, 100000) f32
  float* out = (float*)d_out;
  float* ws = (float*)d_ws;

  float* S1g      = ws;
  float* cntF     = ws + 640;
  int*   meta     = (int*)(ws + 656);
  int*   cursor   = (int*)(ws + 672);
  int*   tileclu  = (int*)(ws + 1024);
  int*   nvalid   = (int*)(ws + 7296);
  int*   inv      = (int*)(ws + 16384);
  unsigned* W2P   = (unsigned*)(ws + 247808);
  float* S1p      = ws + 6647808;
  float* cntp     = ws + 6898688;
  float* bucket   = ws + 6647808;              // overlays S1p (dead after k1r)

  k1_segsum<<<K1B, 256, 0, stream>>>(cl, W1, S1p, cntp);
  k1r<<<1, 256, 0, stream>>>(S1p, cntp, S1g, cntF, meta, tileclu, nvalid,
                             inv, cursor);
  k1c<<<391, 256, 0, stream>>>(cl, meta, cursor, inv, bucket);
  w2p_k<<<(N_ITEMS + 63) / 64, 256, 0, stream>>>(W2, W2P);

  dim3 g3(N_B / 64, GYB);                       // (16, 98)
  k3_mfma<<<g3, 256, 0, stream>>>(W2P, input, S1g, inv, tileclu, nvalid,
                                  bucket);

  k4_fin<<<32, 320, 0, stream>>>(bucket, cntF, out);
}

// Round 2
// 214.163 us; speedup vs baseline: 1.8020x; 1.3823x over previous
//
#include <hip/hip_runtime.h>
#include <hip/hip_bf16.h>

#define N_B 1024
#define N_ITEMS 100000
#define N_CLUSTERS 10
#define N_D 64
#define MAXT 6272            // padded tile capacity; NT <= 6260 always
#define GYB 98               // k3 j-block dim
#define RUN 16               // tiles per wave: 98*4*16 = 6272 exactly
#define K1B 392              // k1 blocks: 392*4 waves*64 rows = 100352

typedef __attribute__((ext_vector_type(8))) short short8;
typedef __attribute__((ext_vector_type(4))) float f32x4;
typedef __attribute__((ext_vector_type(4))) unsigned u32x4;

#if defined(__has_builtin)
#if __has_builtin(__builtin_amdgcn_exp2f)
#define EXP2F(x) __builtin_amdgcn_exp2f(x)
#endif
#endif
#ifndef EXP2F
#define EXP2F(x) exp2f(x)
#endif

// bf16 RNE split helpers (bit-level; sign-safe)
__device__ __forceinline__ unsigned short bf16_rne(float x) {
  unsigned u = __float_as_uint(x);
  u += 0x7FFFu + ((u >> 16) & 1u);
  return (unsigned short)(u >> 16);
}
__device__ __forceinline__ float bf16_f(unsigned short b) {
  return __uint_as_float(((unsigned)b) << 16);
}

// pack low/high 16-bit halves of 8 dwords into a short8 via v_perm_b32
__device__ __forceinline__ short8 pack_even(u32x4 a, u32x4 b) {
  union { unsigned u[4]; short8 s; } r;
  r.u[0] = __builtin_amdgcn_perm(a[1], a[0], 0x05040100u);
  r.u[1] = __builtin_amdgcn_perm(a[3], a[2], 0x05040100u);
  r.u[2] = __builtin_amdgcn_perm(b[1], b[0], 0x05040100u);
  r.u[3] = __builtin_amdgcn_perm(b[3], b[2], 0x05040100u);
  return r.s;
}
__device__ __forceinline__ short8 pack_odd(u32x4 a, u32x4 b) {
  union { unsigned u[4]; short8 s; } r;
  r.u[0] = __builtin_amdgcn_perm(a[1], a[0], 0x07060302u);
  r.u[1] = __builtin_amdgcn_perm(a[3], a[2], 0x07060302u);
  r.u[2] = __builtin_amdgcn_perm(b[1], b[0], 0x07060302u);
  r.u[3] = __builtin_amdgcn_perm(b[3], b[2], 0x07060302u);
  return r.s;
}

// ---------------------------------------------------------------------------
// Kernel 1: per-block partial S1/counts. Also zeroes inv[] (392*256 = 100352
// threads = MAXT*16 slots exactly) so k1r no longer does serial pad fills.
// ---------------------------------------------------------------------------
__global__ __launch_bounds__(256) void k1_segsum(
    const int* __restrict__ cl, const float* __restrict__ W1,
    float* __restrict__ S1p, float* __restrict__ cntp,
    int* __restrict__ inv) {
  __shared__ float s1[4][N_CLUSTERS][N_D];
  __shared__ float scnt[4][N_CLUSTERS];
  int t = threadIdx.x;
  int wave = t >> 6, lane = t & 63;

  inv[blockIdx.x * 256 + t] = 0;               // zero all MAXT*16 slots

  float a[N_CLUSTERS], cn[N_CLUSTERS];
#pragma unroll
  for (int k = 0; k < N_CLUSTERS; ++k) { a[k] = 0.f; cn[k] = 0.f; }

  int gw = blockIdx.x * 4 + wave;              // 0..1567
  int r0 = gw * 64;
#pragma unroll 1
  for (int b = 0; b < 8; ++b) {
    int i0 = r0 + b * 8;
    float w[8];
    int c[8];
    if (i0 + 8 <= N_ITEMS) {
#pragma unroll
      for (int j = 0; j < 8; ++j) {
        c[j] = cl[i0 + j];                     // wave-uniform -> s_load
        w[j] = W1[(size_t)(i0 + j) * N_D + lane];
      }
    } else {
#pragma unroll
      for (int j = 0; j < 8; ++j) {
        int i = i0 + j;
        bool ok = i < N_ITEMS;
        c[j] = ok ? cl[i] : -1;
        w[j] = ok ? W1[(size_t)i * N_D + lane] : 0.f;
      }
    }
#pragma unroll
    for (int j = 0; j < 8; ++j)
#pragma unroll
      for (int k = 0; k < N_CLUSTERS; ++k) {
        bool m = (c[j] == k);
        a[k] += m ? w[j] : 0.f;
        cn[k] += m ? 1.f : 0.f;
      }
  }
#pragma unroll
  for (int k = 0; k < N_CLUSTERS; ++k) s1[wave][k][lane] = a[k];
  if (lane == 0) {
#pragma unroll
    for (int k = 0; k < N_CLUSTERS; ++k) scnt[wave][k] = cn[k];
  }
  __syncthreads();
  const float* fs1 = (const float*)s1;
  for (int i = t; i < N_CLUSTERS * N_D; i += 256) {
    S1p[blockIdx.x * 640 + i] =
        fs1[i] + fs1[640 + i] + fs1[1280 + i] + fs1[1920 + i];
  }
  if (t < N_CLUSTERS) {
    cntp[blockIdx.x * N_CLUSTERS + t] =
        scnt[0][t] + scnt[1][t] + scnt[2][t] + scnt[3][t];
  }
}

// ---------------------------------------------------------------------------
// Kernel 1r (was the 104us bottleneck: one block, 250K serial loads).
// Now light: cursor zero + PARALLEL count reduce (160 threads, coalesced) +
// segment bases + tile tables. S1g reduce moved to k1c blocks 0..9; inv pad
// fills gone (k1 pre-zeroes inv). ~4us.
// ---------------------------------------------------------------------------
__global__ __launch_bounds__(256) void k1r(
    const float* __restrict__ cntp, float* __restrict__ cntF,
    int* __restrict__ meta, int* __restrict__ tileclu,
    int* __restrict__ nvalid, int* __restrict__ cursor) {
  __shared__ int baseS[11];
  __shared__ int cntI[N_CLUSTERS];
  __shared__ float part[16][N_CLUSTERS];
  int t = threadIdx.x;
  if (t < 16) cursor[t] = 0;
  if (t < 160) {                               // coalesced: addr = t + 160*i
    int c = t % N_CLUSTERS, g = t / N_CLUSTERS;
    float s = 0.f;
    for (int b = g; b < K1B; b += 16) s += cntp[b * N_CLUSTERS + c];
    part[g][c] = s;
  }
  __syncthreads();
  if (t < N_CLUSTERS) {
    float s = 0.f;
#pragma unroll
    for (int g = 0; g < 16; ++g) s += part[g][t];
    cntF[t] = s;
    cntI[t] = (int)(s + 0.5f);
  }
  __syncthreads();
  if (t == 0) {
    int acc = 0;
    for (int c = 0; c < N_CLUSTERS; ++c) {
      baseS[c] = acc;
      acc += ((cntI[c] + 15) >> 4) << 4;       // 16-align each segment
    }
    baseS[10] = acc;
    for (int c = 0; c < 11; ++c) meta[c] = baseS[c];
    meta[11] = acc >> 4;                       // NT
  }
  __syncthreads();
  int NT = baseS[10] >> 4;
  for (int jt = t; jt < MAXT; jt += 256) {
    int c = 0, nv = 0;
    if (jt < NT) {
      int p0 = jt * 16;
      for (int k = 0; k < N_CLUSTERS; ++k)
        if (p0 >= baseS[k] && p0 < baseS[k + 1]) c = k;
      nv = min(16, cntI[c] - (p0 - baseS[c]));
      if (nv < 0) nv = 0;
    }
    tileclu[jt] = c;
    nvalid[jt] = nv;
  }
}

// ---------------------------------------------------------------------------
// Kernel 1c: inverse perm (pos -> item), block-aggregated ranking.
// Blocks 0..9 additionally reduce S1p -> S1g (64 cols each, 4 waves x 98
// coalesced 256B loads) — this replaces k1r's serial 250K-load loop.
// Blocks 0..39 zero the atomic bucket array (now overlays dead cntp, NOT
// S1p, which is still read here).
// ---------------------------------------------------------------------------
__global__ __launch_bounds__(256) void k1c(
    const int* __restrict__ cl, const int* __restrict__ meta,
    int* __restrict__ cursor, int* __restrict__ inv,
    const float* __restrict__ S1p, float* __restrict__ S1g,
    float* __restrict__ bucket) {
  __shared__ int wn[4][N_CLUSTERS];
  __shared__ int bb[N_CLUSTERS];
  __shared__ float sgp[4][64];
  int i = blockIdx.x * 256 + threadIdx.x;
  int wave = threadIdx.x >> 6, lane = threadIdx.x & 63;
  if (i < N_B * N_CLUSTERS) bucket[i] = 0.f;   // zero 10240 floats

  if (blockIdx.x < 10) {                       // block-uniform branch
    float s = 0.f;
    const float* sp = S1p + blockIdx.x * 64 + lane;
#pragma unroll 4
    for (int b = wave; b < K1B; b += 4) s += sp[b * 640];
    sgp[wave][lane] = s;
  }

  int c = (i < N_ITEMS) ? cl[i] : -1;
  unsigned long long m[N_CLUSTERS];
#pragma unroll
  for (int k = 0; k < N_CLUSTERS; ++k) {
    m[k] = __ballot(c == k);
    if (lane == 0) wn[wave][k] = __popcll(m[k]);
  }
  __syncthreads();
  if (blockIdx.x < 10 && threadIdx.x < 64) {
    S1g[blockIdx.x * 64 + threadIdx.x] =
        sgp[0][threadIdx.x] + sgp[1][threadIdx.x] +
        sgp[2][threadIdx.x] + sgp[3][threadIdx.x];
  }
  if (threadIdx.x < N_CLUSTERS) {
    int tot = wn[0][threadIdx.x] + wn[1][threadIdx.x] + wn[2][threadIdx.x] +
              wn[3][threadIdx.x];
    bb[threadIdx.x] = tot ? atomicAdd(&cursor[threadIdx.x], tot) : 0;
  }
  __syncthreads();
  if (c >= 0) {
    int rank = 0;
#pragma unroll
    for (int k = 0; k < N_CLUSTERS; ++k)
      if (c == k) rank = __popcll(m[k] & ((1ull << lane) - 1ull));
    int wsum = 0;
    for (int w2 = 0; w2 < wave; ++w2) wsum += wn[w2][c];
    inv[meta[c] + bb[c] + wsum + rank] = i;
  }
}

// ---------------------------------------------------------------------------
// Kernel W2P: transpose + bf16 hi/lo split of W2 (64 x 100000 fp32 ->
// item-major 100000 x 64 packed hi|lo<<16 dwords).
// ---------------------------------------------------------------------------
__global__ __launch_bounds__(256) void w2p_k(const float* __restrict__ W2,
                                             unsigned* __restrict__ W2P) {
  __shared__ unsigned tile[64][65];            // +1 pad: conflict-free
  int t = threadIdx.x;
  int c0 = blockIdx.x * 64;
  int cl_ = t & 63;
  int r0 = t >> 6;
  bool okr = (c0 + cl_) < N_ITEMS;
#pragma unroll
  for (int rr = 0; rr < 16; ++rr) {
    int r = rr * 4 + r0;
    float x = okr ? W2[(size_t)r * N_ITEMS + c0 + cl_] : 0.f;
    unsigned short hi = bf16_rne(x);
    unsigned short lo = bf16_rne(x - bf16_f(hi));
    tile[cl_][r] = (unsigned)hi | ((unsigned)lo << 16);
  }
  __syncthreads();
  int rw = t & 63;
  int cw = t >> 6;
#pragma unroll
  for (int cb = 0; cb < 16; ++cb) {
    int c = c0 + cb * 4 + cw;
    if (c < N_ITEMS) W2P[(size_t)c * N_D + rw] = tile[cb * 4 + cw][rw];
  }
}

// ---------------------------------------------------------------------------
// Kernel 3 (hot): in-block A-fragments from inp @ S1g; B gathered from W2P
// as dwordx4; register exp-accumulate with cluster-change-only flush;
// atomicAdd bucket; XCD swizzle.
// ---------------------------------------------------------------------------
__global__ __launch_bounds__(256, 4) void k3_mfma(
    const unsigned* __restrict__ W2P, const float* __restrict__ inp,
    const float* __restrict__ S1g, const int* __restrict__ inv,
    const int* __restrict__ tileclu, const int* __restrict__ nvalid,
    float* __restrict__ bucket) {
  __shared__ short8 afl[16][64];               // 16 KB A-fragments
  __shared__ int linv[4][256];                 // 4 KB per-wave col staging
  int t = threadIdx.x;
  int wave = t >> 6, lane = t & 63;
  int l15 = lane & 15, quad = lane >> 4;

  // bijective XCD swizzle: 1568 blocks = 8 XCDs x 196
  int lid = blockIdx.y * 16 + blockIdx.x;
  int nid = (lid & 7) * (GYB * 16 / 8) + (lid >> 3);
  int bx = nid & 15, by = nid >> 4;

  int jt0 = (by * 4 + wave) * RUN;             // jt0+RUN <= 6272 always

  {  // stage this run's inv slice (per-wave)
    const int* ip = inv + jt0 * 16;
#pragma unroll
    for (int q = 0; q < 4; ++q) linv[wave][q * 64 + lane] = ip[q * 64 + lane];
  }

  // build A fragments: h = inp @ S1g, * log2(e), bf16 hi/lo split
#pragma unroll
  for (int rep = 0; rep < 2; ++rep) {
    int id = rep * 256 + t;                    // 512 fragment slots
    int fl = id & 63;
    int ks = (id >> 6) & 1;
    int rtl = (id >> 7) & 3;
    int row = bx * 64 + rtl * 16 + (id & 15);
    int d0 = ks * 32 + ((id >> 4) & 3) * 8;
    float hv[8];
#pragma unroll
    for (int j = 0; j < 8; ++j) hv[j] = 0.f;
#pragma unroll
    for (int c = 0; c < N_CLUSTERS; ++c) {
      float ic = inp[row * N_CLUSTERS + c];
      const float* sp = S1g + c * N_D + d0;
#pragma unroll
      for (int j = 0; j < 8; ++j) hv[j] += ic * sp[j];
    }
    short8 hi8, lo8;
#pragma unroll
    for (int j = 0; j < 8; ++j) {
      float x = hv[j] * 1.44269504088896340736f;
      unsigned short us = bf16_rne(x);
      hi8[j] = (short)us;
      lo8[j] = (short)bf16_rne(x - bf16_f(us));
    }
    afl[(rtl * 2 + ks) * 2 + 0][fl] = hi8;
    afl[(rtl * 2 + ks) * 2 + 1][fl] = lo8;
  }
  __syncthreads();

  f32x4 acc[4];
#pragma unroll
  for (int rt = 0; rt < 4; ++rt) acc[rt] = (f32x4){0.f, 0.f, 0.f, 0.f};

  u32x4 va, vb, vc, vd;
  int cc, nv;
  {
    int col = linv[wave][l15];
    const unsigned* bp = W2P + (size_t)col * N_D + quad * 8;
    va = *(const u32x4*)(bp);
    vb = *(const u32x4*)(bp + 4);
    vc = *(const u32x4*)(bp + 32);
    vd = *(const u32x4*)(bp + 36);
    cc = tileclu[jt0];
    nv = nvalid[jt0];
  }

  for (int it = 0; it < RUN; ++it) {
    short8 bh0, bl0, bh1, bl1;
    bool act = (nv > 0);                       // wave-uniform
    if (act) {                                 // unpack frees v for prefetch
      bh0 = pack_even(va, vb);
      bl0 = pack_odd(va, vb);
      bh1 = pack_even(vc, vd);
      bl1 = pack_odd(vc, vd);
    }
    int ccn = cc, nvn = 0;
    if (it + 1 < RUN) {                        // prefetch next tile into v
      int col = linv[wave][(it + 1) * 16 + l15];
      const unsigned* bp = W2P + (size_t)col * N_D + quad * 8;
      va = *(const u32x4*)(bp);
      vb = *(const u32x4*)(bp + 4);
      vc = *(const u32x4*)(bp + 32);
      vd = *(const u32x4*)(bp + 36);
      ccn = tileclu[jt0 + it + 1];
      nvn = nvalid[jt0 + it + 1];
    }
    if (act) {
#pragma unroll
      for (int rt = 0; rt < 4; ++rt) {
        short8 a00 = afl[rt * 4 + 0][lane];
        short8 a01 = afl[rt * 4 + 1][lane];
        short8 a10 = afl[rt * 4 + 2][lane];
        short8 a11 = afl[rt * 4 + 3][lane];
        f32x4 c = {0.f, 0.f, 0.f, 0.f};
        c = __builtin_amdgcn_mfma_f32_16x16x32_bf16(a00, bh0, c, 0, 0, 0);
        c = __builtin_amdgcn_mfma_f32_16x16x32_bf16(a00, bl0, c, 0, 0, 0);
        c = __builtin_amdgcn_mfma_f32_16x16x32_bf16(a01, bh0, c, 0, 0, 0);
        c = __builtin_amdgcn_mfma_f32_16x16x32_bf16(a10, bh1, c, 0, 0, 0);
        c = __builtin_amdgcn_mfma_f32_16x16x32_bf16(a10, bl1, c, 0, 0, 0);
        c = __builtin_amdgcn_mfma_f32_16x16x32_bf16(a11, bh1, c, 0, 0, 0);
        // C/D: col=lane&15 (item), row=quad*4+reg  [m89-verified]
        if (nv == 16) {
          acc[rt][0] += EXP2F(c[0]);
          acc[rt][1] += EXP2F(c[1]);
          acc[rt][2] += EXP2F(c[2]);
          acc[rt][3] += EXP2F(c[3]);
        } else {
          acc[rt][0] += (l15 < nv) ? EXP2F(c[0]) : 0.f;
          acc[rt][1] += (l15 < nv) ? EXP2F(c[1]) : 0.f;
          acc[rt][2] += (l15 < nv) ? EXP2F(c[2]) : 0.f;
          acc[rt][3] += (l15 < nv) ? EXP2F(c[3]) : 0.f;
        }
      }
    }
    if (it == RUN - 1 || ccn != cc) {          // flush (wave-uniform, rare)
#pragma unroll
      for (int rt = 0; rt < 4; ++rt) {
        float e0 = acc[rt][0], e1 = acc[rt][1];
        float e2 = acc[rt][2], e3 = acc[rt][3];
#pragma unroll
        for (int m = 1; m < 16; m <<= 1) {
          e0 += __shfl_xor(e0, m, 64);
          e1 += __shfl_xor(e1, m, 64);
          e2 += __shfl_xor(e2, m, 64);
          e3 += __shfl_xor(e3, m, 64);
        }
        if (l15 == 0) {
          int r = bx * 64 + rt * 16 + quad * 4;
          atomicAdd(&bucket[(r + 0) * N_CLUSTERS + cc], e0);
          atomicAdd(&bucket[(r + 1) * N_CLUSTERS + cc], e1);
          atomicAdd(&bucket[(r + 2) * N_CLUSTERS + cc], e2);
          atomicAdd(&bucket[(r + 3) * N_CLUSTERS + cc], e3);
        }
        acc[rt] = (f32x4){0.f, 0.f, 0.f, 0.f};
      }
    }
    cc = ccn;
    nv = nvn;
  }
}

// ---------------------------------------------------------------------------
// Kernel 4: normalize (softmax denom = per-row sum over clusters), /counts.
// ---------------------------------------------------------------------------
__global__ __launch_bounds__(320) void k4_fin(
    const float* __restrict__ bucket, const float* __restrict__ cntF,
    float* __restrict__ out) {
  __shared__ float bl[32][N_CLUSTERS];
  int t = threadIdx.x;                         // 0..319
  int r = t / N_CLUSTERS, c = t % N_CLUSTERS;
  int row = blockIdx.x * 32 + r;
  float s = bucket[row * N_CLUSTERS + c];
  bl[r][c] = s;
  __syncthreads();
  float tot = 0.f;
#pragma unroll
  for (int k = 0; k < N_CLUSTERS; ++k) tot += bl[r][k];
  out[row * N_CLUSTERS + c] = s / (tot * fmaxf(cntF[c], 1.f));
}

// ---------------------------------------------------------------------------
// Workspace layout (4-byte units), total 27.6 MB:
//   [0,640) S1g | [640,656) cntF | [656,672) meta | [672,688) cursor
//   [1024,7296) tileclu | [7296,13568) nvalid | [16384,116736) inv
//   [247808,6647808) W2P (item-major packed bf16 hi|lo dwords)
//   scratch: [6647808,6898688) S1p (read by k1c blocks 0..9)
//            [6898688,6902608) cntp (dead after k1r)
//   bucket OVERLAYS cntp region: [6898688,6908928) — zeroed in k1c (cntp is
//   dead by then; does NOT overlap S1p, which k1c reads), accumulated in k3,
//   read in k4; stream-ordered.
// No memset: inv zeroed by k1, cursor by k1r, bucket by k1c.
// ---------------------------------------------------------------------------
extern "C" void kernel_launch(void* const* d_in, const int* in_sizes, int n_in,
                              void* d_out, int out_size, void* d_ws, size_t ws_size,
                              hipStream_t stream) {
  const float* input = (const float*)d_in[0];   // (1024, 10) f32
  const int* cl      = (const int*)d_in[1];     // (100000,) i32
  const float* W1    = (const float*)d_in[2];   // (100000, 64) f32
  const float* W2    = (const float*)d_in[3];   // (64, 100000) f32
  float* out = (float*)d_out;
  float* ws = (float*)d_ws;

  float* S1g      = ws;
  float* cntF     = ws + 640;
  int*   meta     = (int*)(ws + 656);
  int*   cursor   = (int*)(ws + 672);
  int*   tileclu  = (int*)(ws + 1024);
  int*   nvalid   = (int*)(ws + 7296);
  int*   inv      = (int*)(ws + 16384);
  unsigned* W2P   = (unsigned*)(ws + 247808);
  float* S1p      = ws + 6647808;
  float* cntp     = ws + 6898688;
  float* bucket   = ws + 6898688;              // overlays cntp (dead after k1r)

  k1_segsum<<<K1B, 256, 0, stream>>>(cl, W1, S1p, cntp, inv);
  k1r<<<1, 256, 0, stream>>>(cntp, cntF, meta, tileclu, nvalid, cursor);
  k1c<<<391, 256, 0, stream>>>(cl, meta, cursor, inv, S1p, S1g, bucket);
  w2p_k<<<(N_ITEMS + 63) / 64, 256, 0, stream>>>(W2, W2P);

  dim3 g3(N_B / 64, GYB);                       // (16, 98)
  k3_mfma<<<g3, 256, 0, stream>>>(W2P, input, S1g, inv, tileclu, nvalid,
                                  bucket);

  k4_fin<<<32, 320, 0, stream>>>(bucket, cntF, out);
}